// Round 13
// baseline (241.478 us; speedup 1.0000x reference)
//
#include <hip/hip_runtime.h>
#include <hip/hip_bf16.h>

// Problem: B=16, C=512, H=W=64 -> HW=4096, fp32.
// attn[b,c,d] = sum_n q[b,c,n]*kv[b,d,n]; P = softmax_d(attn);
// info[b,c,n] = sum_d P[b,c,d]*kv[b,d,n]; out = gamma*info + img.
//
// R13 structure:
//   prep_kv: txt f32 -> kv16 bf16 (d_out lo) + kvT bf16 (ws)   [~45 us, BW floor]
//   gemm_qk: attn partials = img(f32 reg-staged) * kv16^T(gload_lds);
//            NEW: single-buffer 32 KiB serial structure (pv-proven) at
//            SPLITK=4 -> 1024 blocks = exactly 4 blocks/CU; cross-block
//            TLP covers the staging drains (R8/R9/R12 lesson: in-block
//            pipelining never helped these latency-bound GEMMs; 4/CU did).
//   softmax: 4-way partial-sum + row softmax -> P bf16 (R2-proven)
//   gemm_pv: R5-exact (measured 88 us): 512 thr, tile 128x128, wave 64x32,
//            single 32 KiB LDS, gload_lds, img in epilogue, bx-fastest.

constexpr int NB = 16;
constexpr int NC = 512;
constexpr int NHW = 4096;
constexpr int QKSPLIT = 4;

typedef float f32x4 __attribute__((ext_vector_type(4)));
typedef __bf16 bf16x4 __attribute__((ext_vector_type(4)));
typedef __bf16 bf16x8 __attribute__((ext_vector_type(8)));

__device__ __forceinline__ void gload16(const void* g, void* l) {
  __builtin_amdgcn_global_load_lds(
      (const __attribute__((address_space(1))) void*)g,
      (__attribute__((address_space(3))) void*)l, 16, 0, 0);
}

// ---------------------------------------------------------------------------
// gemm_qk: D[m][n'] = sum_k A[m][k]*B[n'][k]; A img f32, B kv16 bf16.
// Tile 128x128, BK=64, 8 waves (2Mx4N), wave tile 64x32.
// SINGLE 32 KiB LDS buffer, serial per k-step (m97/pv structure):
//   loadA(k)[4 vmem] ; stageB(k)[2 gload_lds] ; vmcnt(2)->writeA ;
//   __syncthreads (drains B + ds) ; compute ; __syncthreads.
// 4 blocks/CU: other blocks' compute covers this block's drains.
// ---------------------------------------------------------------------------
template <int SPLITS>
__global__ __launch_bounds__(512) void gemm_qk(const float* __restrict__ Af,
                                               const __bf16* __restrict__ B,
                                               float* __restrict__ Dp) {
  __shared__ __bf16 sA[128 * 64];
  __shared__ __bf16 sB[128 * 64];

  const int t = threadIdx.x;
  const int lane = t & 63;
  const int wave = t >> 6;
  const int wr = wave >> 2;
  const int wc = wave & 3;

  // XCD-aware remap (NWG % 8 == 0). Consecutive ids within an XCD chunk
  // sweep bx,by within one (batch,split) slab (q 2MB + kv16 1MB, L2-fit).
  constexpr int NWG = 16 * NB * SPLITS;  // 1024
  constexpr int QX = NWG / 8;
  int flat = blockIdx.x + 4 * (blockIdx.y + 4 * blockIdx.z);
  flat = (flat & 7) * QX + (flat >> 3);
  const int bx = flat & 3;
  const int by = (flat >> 2) & 3;
  const int bz = flat >> 4;
  const int batch = bz / SPLITS;
  const int split = bz % SPLITS;

  const int aRow0 = bx * 128;
  const int bRow0 = by * 128;
  constexpr int KSUB = NHW / SPLITS;  // 1024
  constexpr int NT = KSUB / 64;       // 16
  const int kBeg = split * KSUB;

  // B staging (gload_lds): rows wave*16 + i*8 + (lane>>3), src chunk XOR
  const int rl = lane >> 3;
  const int csrc = ((lane & 7) ^ rl) * 8;
  const __bf16* Bbase = B + (long)batch * NC * NHW +
                        (long)(bRow0 + wave * 16 + rl) * NHW + csrc + kBeg;
  const int ldsOff = wave * 16 * 64;

  // A staging (f32 regs): k-cols c4..c4+3, rows rb + 32*i
  const int c4 = (t & 15) * 4;
  const int rb = t >> 4;
  const float* Abase =
      Af + (long)batch * NC * NHW + (long)(aRow0 + rb) * NHW + kBeg + c4;

  f32x4 ra[4];
  f32x4 acc[4][2] = {};

#pragma unroll 1
  for (int tt = 0; tt < NT; ++tt) {
    const int kof = tt * 64;
    // issue A loads first (vmcnt counts oldest-first), then B gloads
#pragma unroll
    for (int i = 0; i < 4; ++i)
      ra[i] = *(const f32x4*)(Abase + kof + (long)(32 * i) * NHW);
#pragma unroll
    for (int i = 0; i < 2; ++i)
      gload16(Bbase + kof + (long)(i * 8) * NHW, &sB[ldsOff + i * 8 * 64]);
    asm volatile("s_waitcnt vmcnt(2)" ::: "memory");  // 4 A-loads landed
#pragma unroll
    for (int i = 0; i < 4; ++i) {
      const int r = rb + 32 * i;
      const int idx = r * 64 + (c4 ^ ((r & 7) << 3));
      bf16x4 h = {(__bf16)ra[i].x, (__bf16)ra[i].y, (__bf16)ra[i].z,
                  (__bf16)ra[i].w};
      *(bf16x4*)&sA[idx] = h;
    }
    __syncthreads();  // drains B gloads + A ds_writes (vmcnt0/lgkmcnt0)
#pragma unroll
    for (int kk = 0; kk < 2; ++kk) {
      const int kb = kk * 32 + ((lane >> 4) << 3);
      bf16x8 af[4], bfr[2];
#pragma unroll
      for (int m = 0; m < 4; ++m) {
        const int r = wr * 64 + m * 16 + (lane & 15);
        af[m] = *(const bf16x8*)&sA[r * 64 + (kb ^ ((r & 7) << 3))];
      }
#pragma unroll
      for (int n = 0; n < 2; ++n) {
        const int r = wc * 32 + n * 16 + (lane & 15);
        bfr[n] = *(const bf16x8*)&sB[r * 64 + (kb ^ ((r & 7) << 3))];
      }
#pragma unroll
      for (int m = 0; m < 4; ++m)
#pragma unroll
        for (int n = 0; n < 2; ++n)
          acc[m][n] = __builtin_amdgcn_mfma_f32_16x16x32_bf16(
              af[m], bfr[n], acc[m][n], 0, 0, 0);
    }
    __syncthreads();
  }

  // epilogue: partial store. C/D layout: col=lane&15, row=(lane>>4)*4+reg
  float* D = Dp + ((long)split * NB + batch) * NC * NC;
  const int m0 = aRow0 + wr * 64;
  const int n0 = bRow0 + wc * 32;
#pragma unroll
  for (int m = 0; m < 4; ++m)
#pragma unroll
    for (int n = 0; n < 2; ++n) {
      const int row0 = m0 + m * 16 + ((lane >> 4) << 2);
      const int col = n0 + n * 16 + (lane & 15);
#pragma unroll
      for (int r = 0; r < 4; ++r)
        D[(long)(row0 + r) * NC + col] = acc[m][n][r];
    }
}

// ---------------------------------------------------------------------------
// gemm_pv (R5-exact, measured 88 us): out = gamma*(kvT*P^T)+img.
// 512 thr, 8 waves (2x4), tile 128x128, wave 64x32, single 32 KiB LDS,
// gload_lds both sides, img read in epilogue, bx-fastest order.
// ---------------------------------------------------------------------------
__global__ __launch_bounds__(512) void gemm_pv(const __bf16* __restrict__ A,
                                               const __bf16* __restrict__ B,
                                               const float* __restrict__ img,
                                               const float* __restrict__ gammap,
                                               float* __restrict__ outp) {
  __shared__ __bf16 sA[128 * 64];
  __shared__ __bf16 sB[128 * 64];

  const int t = threadIdx.x;
  const int lane = t & 63;
  const int wave = t >> 6;
  const int wr = wave >> 2;
  const int wc = wave & 3;

  constexpr int GX = NHW / 128;     // 32
  constexpr int NWG = GX * 4 * NB;  // 2048
  constexpr int QX = NWG / 8;
  int flat = blockIdx.x + GX * (blockIdx.y + 4 * blockIdx.z);
  flat = (flat & 7) * QX + (flat >> 3);
  const int bx = flat % GX;
  const int by = (flat / GX) & 3;
  const int batch = flat / (GX * 4);

  const int aRow0 = bx * 128;
  const int bRow0 = by * 128;

  const int rl = lane >> 3;
  const int csrc = ((lane & 7) ^ rl) * 8;
  const __bf16* Abase =
      A + (long)batch * NHW * NC + (long)(aRow0 + wave * 16 + rl) * NC + csrc;
  const __bf16* Bbase =
      B + (long)batch * NC * NC + (long)(bRow0 + wave * 16 + rl) * NC + csrc;
  const int ldsOff = wave * 16 * 64;

  f32x4 acc[4][2] = {};

#pragma unroll 1
  for (int k0 = 0; k0 < NC; k0 += 64) {
#pragma unroll
    for (int i = 0; i < 2; ++i) {
      gload16(Abase + k0 + (long)(i * 8) * NC, &sA[ldsOff + i * 8 * 64]);
      gload16(Bbase + k0 + (long)(i * 8) * NC, &sB[ldsOff + i * 8 * 64]);
    }
    __syncthreads();  // compiler drains vmcnt before barrier (m97 structure)
#pragma unroll
    for (int kk = 0; kk < 2; ++kk) {
      const int kb = kk * 32 + ((lane >> 4) << 3);
      bf16x8 af[4], bfr[2];
#pragma unroll
      for (int m = 0; m < 4; ++m) {
        const int r = wr * 64 + m * 16 + (lane & 15);
        af[m] = *(const bf16x8*)&sA[r * 64 + (kb ^ ((r & 7) << 3))];
      }
#pragma unroll
      for (int n = 0; n < 2; ++n) {
        const int r = wc * 32 + n * 16 + (lane & 15);
        bfr[n] = *(const bf16x8*)&sB[r * 64 + (kb ^ ((r & 7) << 3))];
      }
#pragma unroll
      for (int m = 0; m < 4; ++m)
#pragma unroll
        for (int n = 0; n < 2; ++n)
          acc[m][n] = __builtin_amdgcn_mfma_f32_16x16x32_bf16(
              af[m], bfr[n], acc[m][n], 0, 0, 0);
    }
    __syncthreads();
  }

  // epilogue: out[b][ch][sp] = gamma*acc + img
  const float g = gammap[0];
  const long obase = (long)batch * NC * NHW;
  const int sp0 = aRow0 + wr * 64;
  const int ch0 = bRow0 + wc * 32;
#pragma unroll
  for (int m = 0; m < 4; ++m)
#pragma unroll
    for (int n = 0; n < 2; ++n) {
      const int sp = sp0 + m * 16 + ((lane >> 4) << 2);
      const int ch = ch0 + n * 16 + (lane & 15);
      const long idx = obase + (long)ch * NHW + sp;
      f32x4 iv = *(const f32x4*)(img + idx);
      f32x4 ov;
#pragma unroll
      for (int r = 0; r < 4; ++r) ov[r] = g * acc[m][n][r] + iv[r];
      *(f32x4*)(outp + idx) = ov;
    }
}

// ---------------------------------------------------------------------------
// prep_kv: kv[b][d][n] f32 -> kv16[b][d][n] bf16 AND kvT[b][n][d] bf16.
// ---------------------------------------------------------------------------
__global__ __launch_bounds__(256) void prep_kv(const float* __restrict__ kv,
                                               __bf16* __restrict__ kv16,
                                               __bf16* __restrict__ kvT) {
  __shared__ __bf16 tile[64 * 68];
  const int t = threadIdx.x;
  const int n0 = blockIdx.x * 64;
  const int d0 = blockIdx.y * 64;
  const long ibase = (long)blockIdx.z * NC * NHW;

  const int nc4 = (t & 15) * 4;
  const int dr0 = t >> 4;
#pragma unroll
  for (int i = 0; i < 4; ++i) {
    const int dr = dr0 + 16 * i;
    f32x4 v = *(const f32x4*)(kv + ibase + (long)(d0 + dr) * NHW + n0 + nc4);
    bf16x4 h = {(__bf16)v.x, (__bf16)v.y, (__bf16)v.z, (__bf16)v.w};
    *(bf16x4*)&tile[dr * 68 + nc4] = h;
    *(bf16x4*)(kv16 + ibase + (long)(d0 + dr) * NHW + n0 + nc4) = h;
  }
  __syncthreads();

  const long obase = (long)blockIdx.z * NHW * NC;
  const int nr = t >> 2;
  const int dc0 = t & 3;
#pragma unroll
  for (int i = 0; i < 2; ++i) {
    const int dc = dc0 + 4 * i;
    bf16x8 pk;
#pragma unroll
    for (int j = 0; j < 8; ++j) pk[j] = tile[(dc * 8 + j) * 68 + nr];
    *(bf16x8*)(kvT + obase + (long)(n0 + nr) * NC + d0 + dc * 8) = pk;
  }
}

// ---------------------------------------------------------------------------
// Row softmax with split-K reduction -> P bf16. One wave per row.
// ---------------------------------------------------------------------------
template <int SPLITS>
__global__ __launch_bounds__(256) void softmax_rows(
    const float* __restrict__ attn, __bf16* __restrict__ P) {
  const int row = blockIdx.x * 4 + (threadIdx.x >> 6);
  const int lane = threadIdx.x & 63;
  const long PS = (long)NB * NC * NC;
  const float* src = attn + (long)row * NC;

  float x[8] = {0.f, 0.f, 0.f, 0.f, 0.f, 0.f, 0.f, 0.f};
#pragma unroll
  for (int s = 0; s < SPLITS; ++s) {
    f32x4 v0 = *(const f32x4*)(src + s * PS + lane * 4);
    f32x4 v1 = *(const f32x4*)(src + s * PS + 256 + lane * 4);
#pragma unroll
    for (int r = 0; r < 4; ++r) { x[r] += v0[r]; x[4 + r] += v1[r]; }
  }

  float mx = x[0];
#pragma unroll
  for (int r = 1; r < 8; ++r) mx = fmaxf(mx, x[r]);
#pragma unroll
  for (int off = 32; off >= 1; off >>= 1) mx = fmaxf(mx, __shfl_xor(mx, off));

  float e[8], s = 0.f;
#pragma unroll
  for (int r = 0; r < 8; ++r) { e[r] = __expf(x[r] - mx); s += e[r]; }
#pragma unroll
  for (int off = 32; off >= 1; off >>= 1) s += __shfl_xor(s, off);
  const float inv = 1.0f / s;

  __bf16* dst = P + (long)row * NC;
  bf16x4 h0, h1;
#pragma unroll
  for (int r = 0; r < 4; ++r) {
    h0[r] = (__bf16)(e[r] * inv);
    h1[r] = (__bf16)(e[4 + r] * inv);
  }
  *(bf16x4*)(dst + lane * 4) = h0;
  *(bf16x4*)(dst + 256 + lane * 4) = h1;
}

// ---------------------------------------------------------------------------
extern "C" void kernel_launch(void* const* d_in, const int* in_sizes, int n_in,
                              void* d_out, int out_size, void* d_ws,
                              size_t ws_size, hipStream_t stream) {
  const float* img = (const float*)d_in[0];
  const float* txt = (const float*)d_in[1];
  const float* gamma = (const float*)d_in[2];
  float* out = (float*)d_out;

  const size_t MiB = 1024 * 1024;
  // d_out (128 MiB) scratch until gemm_pv overwrites it:
  //   [0, 64 MiB)    kv16  (bf16, 64 MiB exactly)
  //   [64, 128 MiB)  attnP (4 splits x 16 MiB f32, 64 MiB exactly)
  // Both dead before gemm_pv writes out.
  __bf16* kv16 = (__bf16*)d_out;
  float* attnP = (float*)((char*)d_out + 64 * MiB);
  // ws: [0,64 MiB) kvT, [64,72 MiB) P
  __bf16* kvT = (__bf16*)d_ws;
  __bf16* P = (__bf16*)((char*)d_ws + 64 * MiB);

  // 1) kv prep: bf16 row-major + transposed copies
  prep_kv<<<dim3(NHW / 64, NC / 64, NB), 256, 0, stream>>>(txt, kv16, kvT);

  // 2) attn partials = img(f32) * kv16^T (512x512, K=4096, split 4,
  //    1024 blocks = 4/CU, single-buffer serial structure)
  gemm_qk<QKSPLIT><<<dim3(4, 4, NB * QKSPLIT), 512, 0, stream>>>(
      img, kv16, attnP);

  // 3) P = softmax(sum of 4 partials)
  softmax_rows<QKSPLIT><<<dim3(NB * NC / 4), 256, 0, stream>>>(attnP, P);

  // 4) out = gamma * (kvT * P^T) + img  (K=512, R5-exact structure)
  gemm_pv<<<dim3(NHW / 128, 4, NB), 512, 0, stream>>>(kvT, P, img, gamma, out);
}